// Round 3
// baseline (1748.487 us; speedup 1.0000x reference)
//
#include <hip/hip_runtime.h>
#include <cstdint>
#include <cstddef>

#define NLAYERS 3
#define NN      512
#define DIN     4
#define MTILE   64            // batch rows per workgroup
#define KAUG    544           // 512 (H/T) + 4 (X) + 1 (bias one) + 27 zero pad
#define LDA     552           // LDS row stride in bf16 elems (276 dwords -> 2-way max aliasing)
#define WELEMS  (NN * KAUG)   // one prepared weight matrix, bf16 elems
#define LDS_BYTES (2 * MTILE * LDA * 2)
#define NTHREADS 512          // 8 waves: one 64-col block per wave -> 2 waves/SIMD

typedef __attribute__((ext_vector_type(8))) short short8;   // 8 x bf16 (4 VGPRs)
typedef __attribute__((ext_vector_type(4))) float f32x4;    // MFMA accumulator

__device__ __forceinline__ short f2bf(float f) {
    union { float f; uint32_t u; } v; v.f = f;
    uint32_t r = v.u + 0x7fffu + ((v.u >> 16) & 1u);   // RNE
    return (short)(r >> 16);
}
__device__ __forceinline__ float bf2f(short s) {
    union { uint32_t u; float f; } v; v.u = ((uint32_t)(uint16_t)s) << 16;
    return v.f;
}
__device__ __forceinline__ float sig_(float x)  { return 1.0f / (1.0f + __expf(-x)); }
__device__ __forceinline__ float tanh_(float x) { return 1.0f - 2.0f / (1.0f + __expf(2.0f * x)); }
__device__ __forceinline__ float silu_(float x) { return x / (1.0f + __expf(-x)); }

// ---------------- prep: 12 transposed + augmented bf16 weight matrices in ws ------------
// mat m = layer*4 + {0:F,1:U,2:O1,3:O2}; Bt[n][kk]:
//   kk<512 -> U[kk][n]; 512..515 -> W[kk-512][n] (0 for O2); 516 -> bias[n]; else 0.
__global__ void prep_kernel(const float* __restrict__ Wf,  const float* __restrict__ Uf,  const float* __restrict__ bf,
                            const float* __restrict__ Wu,  const float* __restrict__ Uu,  const float* __restrict__ bu,
                            const float* __restrict__ Wo1, const float* __restrict__ Uo1, const float* __restrict__ bo1,
                            const float* __restrict__ Wo2, const float* __restrict__ bo2,
                            short* __restrict__ ws) {
    int idx = blockIdx.x * 256 + threadIdx.x;
    int m   = idx / WELEMS;
    if (m >= 12) return;
    int rem = idx - m * WELEMS;
    int n   = rem / KAUG;
    int kk  = rem - n * KAUG;
    int layer = m >> 2, t = m & 3;
    const float* U; const float* W; const float* b;
    switch (t) {
        case 0:  U = Uf;  W = Wf;      b = bf;  break;
        case 1:  U = Uu;  W = Wu;      b = bu;  break;
        case 2:  U = Uo1; W = Wo1;     b = bo1; break;
        default: U = Wo2; W = nullptr; b = bo2; break;
    }
    float val = 0.0f;
    if (kk < NN)             val = U[layer * NN * NN + kk * NN + n];
    else if (kk < NN + DIN)  val = W ? W[layer * DIN * NN + (kk - NN) * NN + n] : 0.0f;
    else if (kk == NN + DIN) val = b[layer * NN + n];
    ws[idx] = f2bf(val);
}

// 64x64 @ K=544 MFMA block, fully unrolled straight-line body.
// A: one LDS base, all offsets (mt*16*LDA + k)*2 <= 54 KB fit ds_read's 16-bit imm.
// B: four global bases (one per nt row-block), all k offsets <= 1088 B fit the 13-bit imm.
__device__ __forceinline__ void mm1u(const short* __restrict__ Asrc, const short* __restrict__ Bt,
                                     int n0, int l16, int quad, f32x4 (&acc)[4][4]) {
#pragma unroll
    for (int mt = 0; mt < 4; ++mt)
#pragma unroll
        for (int nt = 0; nt < 4; ++nt) acc[mt][nt] = f32x4{0.f, 0.f, 0.f, 0.f};
    const short* a0 = Asrc + l16 * LDA + quad * 8;
    const short* b0 = Bt + (size_t)(n0 + l16) * KAUG + quad * 8;
    const short* b1 = b0 + 16 * KAUG;
    const short* b2 = b0 + 32 * KAUG;
    const short* b3 = b0 + 48 * KAUG;
#pragma unroll
    for (int ks = 0; ks < KAUG / 32; ++ks) {
        const int k = ks * 32;
        short8 av[4], bv[4];
        av[0] = *(const short8*)(a0 + 0 * 16 * LDA + k);
        av[1] = *(const short8*)(a0 + 1 * 16 * LDA + k);
        av[2] = *(const short8*)(a0 + 2 * 16 * LDA + k);
        av[3] = *(const short8*)(a0 + 3 * 16 * LDA + k);
        bv[0] = *(const short8*)(b0 + k);
        bv[1] = *(const short8*)(b1 + k);
        bv[2] = *(const short8*)(b2 + k);
        bv[3] = *(const short8*)(b3 + k);
#pragma unroll
        for (int mt = 0; mt < 4; ++mt)
#pragma unroll
            for (int nt = 0; nt < 4; ++nt)
                acc[mt][nt] = __builtin_amdgcn_mfma_f32_16x16x32_bf16(av[mt], bv[nt], acc[mt][nt], 0, 0, 0);
    }
}

// ---------------- fused DGM kernel: one 8-wave workgroup = 64 batch rows -----------------
__global__ void __launch_bounds__(NTHREADS, 2)
dgm_kernel(const float* __restrict__ X, const float* __restrict__ W_in, const float* __restrict__ b_in,
           const float* __restrict__ W_out, const float* __restrict__ b_out,
           const short* __restrict__ wmats, float* __restrict__ out) {
    extern __shared__ short lds[];
    short* Hb = lds;                 // [MTILE][LDA]  bf16, cols 512..516 = [X|1]
    short* Tb = lds + MTILE * LDA;   // [MTILE][LDA]  bf16, same augmentation (0,0,0,0,1)

    const int tid  = threadIdx.x;
    const int lane = tid & 63;
    const int wv   = tid >> 6;       // wave 0..7
    const int l16  = lane & 15;
    const int quad = lane >> 4;
    const int n0   = wv * 64;        // this wave's 64-column block
    const int rbase = blockIdx.x * MTILE;

    // ---- H = silu(X @ W_in + b_in), plus one-time augmentation columns ----
#pragma unroll 4
    for (int j = 0; j < (MTILE * NN) / NTHREADS; ++j) {
        int idx = tid + j * NTHREADS;
        int r = idx >> 9;
        int c = idx & (NN - 1);
        const float* xr = X + (size_t)(rbase + r) * DIN;
        float v = b_in[c];
#pragma unroll
        for (int k = 0; k < DIN; ++k) v += xr[k] * W_in[k * NN + c];
        Hb[r * LDA + c] = f2bf(silu_(v));
    }
    if (tid < MTILE) {
        int r = tid;
        const float* xr = X + (size_t)(rbase + r) * DIN;
#pragma unroll
        for (int k = 0; k < DIN; ++k) {
            Hb[r * LDA + NN + k] = f2bf(xr[k]);
            Tb[r * LDA + NN + k] = 0;
        }
        Hb[r * LDA + NN + DIN] = f2bf(1.0f);
        Tb[r * LDA + NN + DIN] = f2bf(1.0f);
        for (int k = NN + DIN + 1; k < KAUG; ++k) {
            Hb[r * LDA + k] = 0;
            Tb[r * LDA + k] = 0;
        }
    }
    __syncthreads();

    uint32_t Fpack[32];   // sigmoid(F) for this wave's 64x64 tile, packed bf16 pairs

    for (int layer = 0; layer < NLAYERS; ++layer) {
        const short* wF  = wmats + (size_t)(layer * 4 + 0) * WELEMS;
        const short* wU  = wmats + (size_t)(layer * 4 + 1) * WELEMS;
        const short* wO1 = wmats + (size_t)(layer * 4 + 2) * WELEMS;
        const short* wO2 = wmats + (size_t)(layer * 4 + 3) * WELEMS;

        // ---- Phase A: T = sigmoid(pre_U)*tanh(pre_O1) -> Tb; F kept packed in regs ----
        uint32_t Tpack[32];
        {
            f32x4 aO[4][4];
            mm1u(Hb, wO1, n0, l16, quad, aO);
#pragma unroll
            for (int mt = 0; mt < 4; ++mt)
#pragma unroll
                for (int nt = 0; nt < 4; ++nt)
#pragma unroll
                    for (int rp = 0; rp < 2; ++rp) {
                        uint32_t lo = (uint16_t)f2bf(tanh_(aO[mt][nt][2 * rp + 0]));
                        uint32_t hi = (uint16_t)f2bf(tanh_(aO[mt][nt][2 * rp + 1]));
                        Tpack[mt * 8 + nt * 2 + rp] = lo | (hi << 16);
                    }
        }
        {
            f32x4 aU[4][4];
            mm1u(Hb, wU, n0, l16, quad, aU);
#pragma unroll
            for (int mt = 0; mt < 4; ++mt)
#pragma unroll
                for (int nt = 0; nt < 4; ++nt)
#pragma unroll
                    for (int rg = 0; rg < 4; ++rg) {
                        uint32_t tp = Tpack[mt * 8 + nt * 2 + (rg >> 1)];
                        float to = bf2f((short)(uint16_t)((rg & 1) ? (tp >> 16) : (tp & 0xffffu)));
                        int row = mt * 16 + quad * 4 + rg;
                        int col = n0 + nt * 16 + l16;
                        Tb[row * LDA + col] = f2bf(sig_(aU[mt][nt][rg]) * to);
                    }
        }
        {
            f32x4 aF[4][4];
            mm1u(Hb, wF, n0, l16, quad, aF);
#pragma unroll
            for (int mt = 0; mt < 4; ++mt)
#pragma unroll
                for (int nt = 0; nt < 4; ++nt)
#pragma unroll
                    for (int rp = 0; rp < 2; ++rp) {
                        uint32_t lo = (uint16_t)f2bf(sig_(aF[mt][nt][2 * rp + 0]));
                        uint32_t hi = (uint16_t)f2bf(sig_(aF[mt][nt][2 * rp + 1]));
                        Fpack[mt * 8 + nt * 2 + rp] = lo | (hi << 16);
                    }
        }
        __syncthreads();   // Tb complete everywhere; Hb reads as A-operand done

        // ---- Phase B: O2 = silu(T @ Wo2 + bo2); H = F*H + O2 (own tile only) ----
        {
            f32x4 aO2[4][4];
            mm1u(Tb, wO2, n0, l16, quad, aO2);
#pragma unroll
            for (int mt = 0; mt < 4; ++mt)
#pragma unroll
                for (int nt = 0; nt < 4; ++nt)
#pragma unroll
                    for (int rg = 0; rg < 4; ++rg) {
                        uint32_t fp = Fpack[mt * 8 + nt * 2 + (rg >> 1)];
                        float f = bf2f((short)(uint16_t)((rg & 1) ? (fp >> 16) : (fp & 0xffffu)));
                        int row = mt * 16 + quad * 4 + rg;
                        int col = n0 + nt * 16 + l16;
                        float hold = bf2f(Hb[row * LDA + col]);
                        float o2 = silu_(aO2[mt][nt][rg]);
                        Hb[row * LDA + col] = f2bf(f * hold + o2);
                    }
        }
        __syncthreads();   // Hb fully updated before next layer reads all of it
    }

    // ---- out = silu(H @ W_out + b_out) ----
    {
        const int r = tid >> 3, q = tid & 7;
        const int c0 = q * (NN / 8);
        float p = 0.0f;
        for (int c = c0; c < c0 + NN / 8; ++c)
            p += bf2f(Hb[r * LDA + c]) * W_out[c];
        float* red = (float*)Tb;     // Tb is free now
        red[tid] = p;
        __syncthreads();
        if (q == 0) {
            float s = b_out[0];
#pragma unroll
            for (int i = 0; i < 8; ++i) s += red[r * 8 + i];
            out[rbase + r] = silu_(s);
        }
    }
}

extern "C" void kernel_launch(void* const* d_in, const int* in_sizes, int n_in,
                              void* d_out, int out_size, void* d_ws, size_t ws_size,
                              hipStream_t stream) {
    const float* X     = (const float*)d_in[0];
    const float* W_in  = (const float*)d_in[1];
    const float* b_in  = (const float*)d_in[2];
    const float* Wf    = (const float*)d_in[3];
    const float* Uf    = (const float*)d_in[4];
    const float* bf    = (const float*)d_in[5];
    const float* Wu    = (const float*)d_in[6];
    const float* Uu    = (const float*)d_in[7];
    const float* bu    = (const float*)d_in[8];
    const float* Wo1   = (const float*)d_in[9];
    const float* Uo1   = (const float*)d_in[10];
    const float* bo1   = (const float*)d_in[11];
    const float* Wo2   = (const float*)d_in[12];
    const float* bo2   = (const float*)d_in[13];
    const float* W_out = (const float*)d_in[14];
    const float* b_out = (const float*)d_in[15];
    float* out = (float*)d_out;
    short* ws  = (short*)d_ws;       // needs 12*512*544*2 = 6.7 MB

    const int B = in_sizes[0] / DIN;

    prep_kernel<<<(12 * WELEMS + 255) / 256, 256, 0, stream>>>(
        Wf, Uf, bf, Wu, Uu, bu, Wo1, Uo1, bo1, Wo2, bo2, ws);

    hipFuncSetAttribute((const void*)dgm_kernel,
                        hipFuncAttributeMaxDynamicSharedMemorySize, LDS_BYTES);
    dgm_kernel<<<B / MTILE, NTHREADS, LDS_BYTES, stream>>>(X, W_in, b_in, W_out, b_out, ws, out);
}

// Round 4
// 1335.043 us; speedup vs baseline: 1.3097x; 1.3097x over previous
//
#include <hip/hip_runtime.h>
#include <cstdint>
#include <cstddef>

#define NLAYERS 3
#define NN      512
#define DIN     4
#define MTILE   64            // batch rows per workgroup
#define KAUG    544           // 512 (H/T) + 4 (X) + 1 (bias one) + 27 zero pad
#define LDA     552           // LDS row stride in bf16 elems
#define WELEMS  (NN * KAUG)   // one prepared weight matrix, bf16 elems
#define LDS_BYTES (2 * MTILE * LDA * 2)
#define NTHREADS 1024         // 16 waves: one 32-col block per wave -> 4 waves/SIMD

typedef __attribute__((ext_vector_type(8))) short short8;   // 8 x bf16 (4 VGPRs)
typedef __attribute__((ext_vector_type(4))) float f32x4;    // MFMA accumulator

__device__ __forceinline__ short f2bf(float f) {
    union { float f; uint32_t u; } v; v.f = f;
    uint32_t r = v.u + 0x7fffu + ((v.u >> 16) & 1u);   // RNE
    return (short)(r >> 16);
}
__device__ __forceinline__ float bf2f(short s) {
    union { uint32_t u; float f; } v; v.u = ((uint32_t)(uint16_t)s) << 16;
    return v.f;
}
__device__ __forceinline__ float sig_(float x)  { return 1.0f / (1.0f + __expf(-x)); }
__device__ __forceinline__ float tanh_(float x) { return 1.0f - 2.0f / (1.0f + __expf(2.0f * x)); }
__device__ __forceinline__ float silu_(float x) { return x / (1.0f + __expf(-x)); }

// ---------------- prep: 12 transposed + augmented bf16 weight matrices in ws ------------
// mat m = layer*4 + {0:F,1:U,2:O1,3:O2}; Bt[n][kk]:
//   kk<512 -> U[kk][n]; 512..515 -> W[kk-512][n] (0 for O2); 516 -> bias[n]; else 0.
__global__ void prep_kernel(const float* __restrict__ Wf,  const float* __restrict__ Uf,  const float* __restrict__ bf,
                            const float* __restrict__ Wu,  const float* __restrict__ Uu,  const float* __restrict__ bu,
                            const float* __restrict__ Wo1, const float* __restrict__ Uo1, const float* __restrict__ bo1,
                            const float* __restrict__ Wo2, const float* __restrict__ bo2,
                            short* __restrict__ ws) {
    int idx = blockIdx.x * 256 + threadIdx.x;
    int m   = idx / WELEMS;
    if (m >= 12) return;
    int rem = idx - m * WELEMS;
    int n   = rem / KAUG;
    int kk  = rem - n * KAUG;
    int layer = m >> 2, t = m & 3;
    const float* U; const float* W; const float* b;
    switch (t) {
        case 0:  U = Uf;  W = Wf;      b = bf;  break;
        case 1:  U = Uu;  W = Wu;      b = bu;  break;
        case 2:  U = Uo1; W = Wo1;     b = bo1; break;
        default: U = Wo2; W = nullptr; b = bo2; break;
    }
    float val = 0.0f;
    if (kk < NN)             val = U[layer * NN * NN + kk * NN + n];
    else if (kk < NN + DIN)  val = W ? W[layer * DIN * NN + (kk - NN) * NN + n] : 0.0f;
    else if (kk == NN + DIN) val = b[layer * NN + n];
    ws[idx] = f2bf(val);
}

// 64x32 @ K=544 MFMA block: A from LDS, Bt from global.
// Register double-buffered, unroll-1 loop (R2 structure — proven not to spill),
// base pointers bumped by 64 elems/iter so all loads use immediate offsets.
__device__ __forceinline__ void mm1(const short* __restrict__ Asrc, const short* __restrict__ Bt,
                                    int n0, int l16, int quad, f32x4 (&acc)[4][2]) {
#pragma unroll
    for (int mt = 0; mt < 4; ++mt)
#pragma unroll
        for (int nt = 0; nt < 2; ++nt) acc[mt][nt] = f32x4{0.f, 0.f, 0.f, 0.f};
    const short* aP = Asrc + l16 * LDA + quad * 8;
    const short* bP = Bt + (size_t)(n0 + l16) * KAUG + quad * 8;

    short8 aA[4], bA[2], aB[4], bB[2];
#pragma unroll
    for (int mt = 0; mt < 4; ++mt) aA[mt] = *(const short8*)(aP + mt * 16 * LDA);
    bA[0] = *(const short8*)(bP);
    bA[1] = *(const short8*)(bP + 16 * KAUG);

#pragma unroll 1
    for (int i = 0; i < 8; ++i) {
#pragma unroll
        for (int mt = 0; mt < 4; ++mt) aB[mt] = *(const short8*)(aP + mt * 16 * LDA + 32);
        bB[0] = *(const short8*)(bP + 32);
        bB[1] = *(const short8*)(bP + 16 * KAUG + 32);
#pragma unroll
        for (int mt = 0; mt < 4; ++mt) {
            acc[mt][0] = __builtin_amdgcn_mfma_f32_16x16x32_bf16(aA[mt], bA[0], acc[mt][0], 0, 0, 0);
            acc[mt][1] = __builtin_amdgcn_mfma_f32_16x16x32_bf16(aA[mt], bA[1], acc[mt][1], 0, 0, 0);
        }
#pragma unroll
        for (int mt = 0; mt < 4; ++mt) aA[mt] = *(const short8*)(aP + mt * 16 * LDA + 64);
        bA[0] = *(const short8*)(bP + 64);
        bA[1] = *(const short8*)(bP + 16 * KAUG + 64);
#pragma unroll
        for (int mt = 0; mt < 4; ++mt) {
            acc[mt][0] = __builtin_amdgcn_mfma_f32_16x16x32_bf16(aB[mt], bB[0], acc[mt][0], 0, 0, 0);
            acc[mt][1] = __builtin_amdgcn_mfma_f32_16x16x32_bf16(aB[mt], bB[1], acc[mt][1], 0, 0, 0);
        }
        aP += 64; bP += 64;
    }
#pragma unroll
    for (int mt = 0; mt < 4; ++mt) {
        acc[mt][0] = __builtin_amdgcn_mfma_f32_16x16x32_bf16(aA[mt], bA[0], acc[mt][0], 0, 0, 0);
        acc[mt][1] = __builtin_amdgcn_mfma_f32_16x16x32_bf16(aA[mt], bA[1], acc[mt][1], 0, 0, 0);
    }
}

// ---------------- fused DGM kernel: one 16-wave workgroup = 64 batch rows ----------------
__global__ void __launch_bounds__(NTHREADS, 4)
dgm_kernel(const float* __restrict__ X, const float* __restrict__ W_in, const float* __restrict__ b_in,
           const float* __restrict__ W_out, const float* __restrict__ b_out,
           const short* __restrict__ wmats, float* __restrict__ out) {
    extern __shared__ short lds[];
    short* Hb = lds;                 // [MTILE][LDA]  bf16, cols 512..516 = [X|1]
    short* Tb = lds + MTILE * LDA;   // [MTILE][LDA]  bf16, same augmentation (0,0,0,0,1)

    const int tid  = threadIdx.x;
    const int lane = tid & 63;
    const int wv   = tid >> 6;       // wave 0..15
    const int l16  = lane & 15;
    const int quad = lane >> 4;
    const int n0   = wv * 32;        // this wave's 32-column block
    const int rbase = blockIdx.x * MTILE;

    // ---- H = silu(X @ W_in + b_in), plus one-time augmentation columns ----
#pragma unroll 4
    for (int j = 0; j < (MTILE * NN) / NTHREADS; ++j) {
        int idx = tid + j * NTHREADS;
        int r = idx >> 9;
        int c = idx & (NN - 1);
        const float* xr = X + (size_t)(rbase + r) * DIN;
        float v = b_in[c];
#pragma unroll
        for (int k = 0; k < DIN; ++k) v += xr[k] * W_in[k * NN + c];
        Hb[r * LDA + c] = f2bf(silu_(v));
    }
    if (tid < MTILE) {
        int r = tid;
        const float* xr = X + (size_t)(rbase + r) * DIN;
#pragma unroll
        for (int k = 0; k < DIN; ++k) {
            Hb[r * LDA + NN + k] = f2bf(xr[k]);
            Tb[r * LDA + NN + k] = 0;
        }
        Hb[r * LDA + NN + DIN] = f2bf(1.0f);
        Tb[r * LDA + NN + DIN] = f2bf(1.0f);
        for (int k = NN + DIN + 1; k < KAUG; ++k) {
            Hb[r * LDA + k] = 0;
            Tb[r * LDA + k] = 0;
        }
    }
    __syncthreads();

    uint32_t Fpack[16];   // sigmoid(F) for this wave's 64x32 tile, packed bf16 pairs

    for (int layer = 0; layer < NLAYERS; ++layer) {
        const short* wF  = wmats + (size_t)(layer * 4 + 0) * WELEMS;
        const short* wU  = wmats + (size_t)(layer * 4 + 1) * WELEMS;
        const short* wO1 = wmats + (size_t)(layer * 4 + 2) * WELEMS;
        const short* wO2 = wmats + (size_t)(layer * 4 + 3) * WELEMS;

        // ---- Phase A: T = sigmoid(pre_U)*tanh(pre_O1) -> Tb; F kept packed in regs ----
        uint32_t Tpack[16];
        {
            f32x4 aO[4][2];
            mm1(Hb, wO1, n0, l16, quad, aO);
#pragma unroll
            for (int mt = 0; mt < 4; ++mt)
#pragma unroll
                for (int nt = 0; nt < 2; ++nt)
#pragma unroll
                    for (int rp = 0; rp < 2; ++rp) {
                        uint32_t lo = (uint16_t)f2bf(tanh_(aO[mt][nt][2 * rp + 0]));
                        uint32_t hi = (uint16_t)f2bf(tanh_(aO[mt][nt][2 * rp + 1]));
                        Tpack[mt * 4 + nt * 2 + rp] = lo | (hi << 16);
                    }
        }
        {
            f32x4 aU[4][2];
            mm1(Hb, wU, n0, l16, quad, aU);
#pragma unroll
            for (int mt = 0; mt < 4; ++mt)
#pragma unroll
                for (int nt = 0; nt < 2; ++nt)
#pragma unroll
                    for (int rg = 0; rg < 4; ++rg) {
                        uint32_t tp = Tpack[mt * 4 + nt * 2 + (rg >> 1)];
                        float to = bf2f((short)(uint16_t)((rg & 1) ? (tp >> 16) : (tp & 0xffffu)));
                        int row = mt * 16 + quad * 4 + rg;
                        int col = n0 + nt * 16 + l16;
                        Tb[row * LDA + col] = f2bf(sig_(aU[mt][nt][rg]) * to);
                    }
        }
        {
            f32x4 aF[4][2];
            mm1(Hb, wF, n0, l16, quad, aF);
#pragma unroll
            for (int mt = 0; mt < 4; ++mt)
#pragma unroll
                for (int nt = 0; nt < 2; ++nt)
#pragma unroll
                    for (int rp = 0; rp < 2; ++rp) {
                        uint32_t lo = (uint16_t)f2bf(sig_(aF[mt][nt][2 * rp + 0]));
                        uint32_t hi = (uint16_t)f2bf(sig_(aF[mt][nt][2 * rp + 1]));
                        Fpack[mt * 4 + nt * 2 + rp] = lo | (hi << 16);
                    }
        }
        __syncthreads();   // Tb complete everywhere; Hb reads as A-operand done

        // ---- Phase B: O2 = silu(T @ Wo2 + bo2); H = F*H + O2 (own tile only) ----
        {
            f32x4 aO2[4][2];
            mm1(Tb, wO2, n0, l16, quad, aO2);
#pragma unroll
            for (int mt = 0; mt < 4; ++mt)
#pragma unroll
                for (int nt = 0; nt < 2; ++nt)
#pragma unroll
                    for (int rg = 0; rg < 4; ++rg) {
                        uint32_t fp = Fpack[mt * 4 + nt * 2 + (rg >> 1)];
                        float f = bf2f((short)(uint16_t)((rg & 1) ? (fp >> 16) : (fp & 0xffffu)));
                        int row = mt * 16 + quad * 4 + rg;
                        int col = n0 + nt * 16 + l16;
                        float hold = bf2f(Hb[row * LDA + col]);
                        float o2 = silu_(aO2[mt][nt][rg]);
                        Hb[row * LDA + col] = f2bf(f * hold + o2);
                    }
        }
        __syncthreads();   // Hb fully updated before next layer reads all of it
    }

    // ---- out = silu(H @ W_out + b_out) ----
    {
        const int r = tid >> 4, q = tid & 15;
        const int c0 = q * (NN / 16);
        float p = 0.0f;
        for (int c = c0; c < c0 + NN / 16; ++c)
            p += bf2f(Hb[r * LDA + c]) * W_out[c];
        float* red = (float*)Tb;     // Tb is free now
        red[tid] = p;
        __syncthreads();
        if (q == 0) {
            float s = b_out[0];
#pragma unroll
            for (int i = 0; i < 16; ++i) s += red[r * 16 + i];
            out[rbase + r] = silu_(s);
        }
    }
}

extern "C" void kernel_launch(void* const* d_in, const int* in_sizes, int n_in,
                              void* d_out, int out_size, void* d_ws, size_t ws_size,
                              hipStream_t stream) {
    const float* X     = (const float*)d_in[0];
    const float* W_in  = (const float*)d_in[1];
    const float* b_in  = (const float*)d_in[2];
    const float* Wf    = (const float*)d_in[3];
    const float* Uf    = (const float*)d_in[4];
    const float* bf    = (const float*)d_in[5];
    const float* Wu    = (const float*)d_in[6];
    const float* Uu    = (const float*)d_in[7];
    const float* bu    = (const float*)d_in[8];
    const float* Wo1   = (const float*)d_in[9];
    const float* Uo1   = (const float*)d_in[10];
    const float* bo1   = (const float*)d_in[11];
    const float* Wo2   = (const float*)d_in[12];
    const float* bo2   = (const float*)d_in[13];
    const float* W_out = (const float*)d_in[14];
    const float* b_out = (const float*)d_in[15];
    float* out = (float*)d_out;
    short* ws  = (short*)d_ws;       // needs 12*512*544*2 = 6.7 MB

    const int B = in_sizes[0] / DIN;

    prep_kernel<<<(12 * WELEMS + 255) / 256, 256, 0, stream>>>(
        Wf, Uf, bf, Wu, Uu, bu, Wo1, Uo1, bo1, Wo2, bo2, ws);

    hipFuncSetAttribute((const void*)dgm_kernel,
                        hipFuncAttributeMaxDynamicSharedMemorySize, LDS_BYTES);
    dgm_kernel<<<B / MTILE, NTHREADS, LDS_BYTES, stream>>>(X, W_in, b_in, W_out, b_out, ws, out);
}